// Round 13
// baseline (2574.662 us; speedup 1.0000x reference)
//
#include <hip/hip_runtime.h>
#include <hip/hip_bf16.h>
#include <math.h>

// Model dims
#define Bq   16
#define Tq   128
#define Hq   512
#define Dq   256
#define G4H  2048            // 4*H
#define MR   2048            // B*T rows
#define VO   32001           // VOUT+1
#define NPAD 32128           // VO padded to multiple of 128
#define BH   (Bq * Hq)       // 8192
#define SENTW 0x7FC0u        // bf16 NaN sentinel (h is bounded, never NaN)
#define SENT64 0x7FC07FC07FC07FC0ull
#define SPINCAP (1 << 20)    // bounded spins: wrong-answer-not-hang on bug
#define FSTRIDE 32           // flag words 128B apart (one per producer rank)

typedef unsigned int u32;
typedef unsigned long long u64;
typedef __attribute__((ext_vector_type(4))) float f32x4;
typedef __attribute__((ext_vector_type(8))) short bfrag;   // 8 x bf16 (4 VGPRs)
typedef __attribute__((ext_vector_type(4))) float facc;    // mfma accumulator

__device__ __forceinline__ float bf2f(short s) {
  union { unsigned u; float f; } v; v.u = ((unsigned)(unsigned short)s) << 16; return v.f;
}
__device__ __forceinline__ short f2bf(float f) {
  union { float f; unsigned u; } v; v.f = f;
  unsigned r = (v.u + 0x7fffu + ((v.u >> 16) & 1u)) >> 16;
  return (short)r;
}
__device__ __forceinline__ float asf(u32 u) {
  union { u32 u; float f; } v; v.u = u; return v.f;
}
__device__ __forceinline__ float sigm(float x) { return 1.0f / (1.0f + expf(-x)); }

__device__ __forceinline__ void ic_store64(u64* p, u64 v) {
  __hip_atomic_store(p, v, __ATOMIC_RELAXED, __HIP_MEMORY_SCOPE_AGENT);
}
__device__ __forceinline__ u64 ic_load64(const u64* p) {
  return __hip_atomic_load(p, __ATOMIC_RELAXED, __HIP_MEMORY_SCOPE_AGENT);
}
__device__ __forceinline__ void ic_store32(u32* p, u32 v) {
  __hip_atomic_store(p, v, __ATOMIC_RELAXED, __HIP_MEMORY_SCOPE_AGENT);
}
__device__ __forceinline__ u32 ic_load32(const u32* p) {
  return __hip_atomic_load(p, __ATOMIC_RELAXED, __HIP_MEMORY_SCOPE_AGENT);
}

// ---- XOR-swizzled LDS addressing for a [16][520]-short plane (row stride 1040B)
__device__ __forceinline__ void* swz(void* plane, int row, int byteoff) {
  return (void*)((char*)plane + row * 1040 + (byteoff ^ ((row & 7) << 4)));
}

// ---- stage helper (plane pair = hi/lo, 16 rows x 256 u32 each)
__device__ __forceinline__ void stage_h(void* p0, void* p1, const u64 v[8]) {
  #pragma unroll
  for (int it = 0; it < 8; ++it) {
    int i = it * 512 + threadIdx.x;
    int b = i >> 8, bo = (i & 255) * 4;
    *(u32*)swz(p0, b, bo) = (u32)v[it];
    *(u32*)swz(p1, b, bo) = (u32)(v[it] >> 32);
  }
}

// ---- cheap ready-wait: ONE wave polls 32 rank-flags (128B), others park at sync.
__device__ __forceinline__ void waitf(const u32* f, u32 need) {
  if (threadIdx.x < 32) {
    u32 v; int spin = 0;
    do {
      v = ic_load32(&f[threadIdx.x * FSTRIDE]);
      if (v < need) __builtin_amdgcn_s_sleep(2);
    } while (v < need && ++spin < SPINCAP);
  }
  __syncthreads();
}
__device__ __forceinline__ void waitf2(const u32* fa, u32 na, const u32* fb, u32 nb) {
  if (threadIdx.x < 32) {
    u32 v; int spin = 0;
    do {
      v = ic_load32(&fa[threadIdx.x * FSTRIDE]);
      if (v < na) __builtin_amdgcn_s_sleep(2);
    } while (v < na && ++spin < SPINCAP);
  } else if (threadIdx.x >= 64 && threadIdx.x < 96) {
    u32 v; int spin = 0;
    do {
      v = ic_load32(&fb[(threadIdx.x - 64) * FSTRIDE]);
      if (v < nb) __builtin_amdgcn_s_sleep(2);
    } while (v < nb && ++spin < SPINCAP);
  }
  __syncthreads();
}

// ---------------- per-launch fills
__global__ __launch_bounds__(256) void k_fill(u64* __restrict__ p, int n) {
  int i = blockIdx.x * 256 + threadIdx.x;
  if (i < n) p[i] = SENT64;
}
__global__ __launch_bounds__(256) void k_fill0(u32* __restrict__ p, int n) {
  int i = blockIdx.x * 256 + threadIdx.x;
  if (i < n) p[i] = 0u;
}

// ---------------- transpose + f32->bf16 (+ optional gate-interleave col perm)
__global__ __launch_bounds__(256) void k_transcvt(const float* __restrict__ in,
                                                  short* __restrict__ out,
                                                  int R, int N, int perm) {
  __shared__ float tile[32][33];
  int nb = blockIdx.x * 32, rb = blockIdx.y * 32;
  int tx = threadIdx.x & 31, ty = threadIdx.x >> 5;
  for (int i = 0; i < 4; ++i) {
    int r = rb + ty + i * 8;
    int n = nb + tx;
    tile[ty + i * 8][tx] = (n < N) ? in[(size_t)r * N + n] : 0.0f;
  }
  __syncthreads();
  for (int i = 0; i < 4; ++i) {
    int n = nb + ty + i * 8;
    int orow = perm ? (((n & 511) << 2) | (n >> 9)) : n;
    out[(size_t)orow * R + rb + tx] = f2bf(tile[tx][ty + i * 8]);
  }
}

// ---------------- embedding gather -> x_bf [T*B, D] bf16
__global__ __launch_bounds__(256) void k_gather(const int* __restrict__ tokens,
                                                const float* __restrict__ emb,
                                                short* __restrict__ xbf) {
  int row = blockIdx.x;                 // t*16+b
  int t = row >> 4, b = row & 15;
  int tok = tokens[b * Tq + t];
  xbf[(size_t)row * Dq + threadIdx.x] = f2bf(emb[(size_t)tok * Dq + threadIdx.x]);
}

// ---------------- bf16 MFMA GEMM: C[M,ldc] = A[M,K] @ BT[Npad,K]^T + bias
__global__ __launch_bounds__(256) void k_gemm(const short* __restrict__ A,
                                              const short* __restrict__ BT,
                                              float* __restrict__ C,
                                              const float* __restrict__ bias,
                                              int M, int Nreal, int K, int ldc,
                                              int permb) {
  __shared__ short lA[128 * 64];
  __shared__ short lB[128 * 64];
  const int tid = threadIdx.x;
  const int wave = tid >> 6, lane = tid & 63;
  const int l15 = lane & 15, l4 = lane >> 4;
  const int m0 = blockIdx.y * 128, n0 = blockIdx.x * 128;
  const int wm = (wave >> 1) * 64, wn = (wave & 1) * 64;
  facc acc[4][4] = {};

  for (int k0 = 0; k0 < K; k0 += 64) {
    __syncthreads();
    for (int i = 0; i < 4; ++i) {
      int c = i * 256 + wave * 64 + lane;
      int r = c >> 3, q = c & 7;
      int qs = q ^ (r & 7);
      const short* ga = A + (size_t)(m0 + r) * K + k0 + qs * 8;
      const short* gb = BT + (size_t)(n0 + r) * K + k0 + qs * 8;
      short* la = lA + (size_t)(i * 256 + wave * 64) * 8;
      short* lb = lB + (size_t)(i * 256 + wave * 64) * 8;
      __builtin_amdgcn_global_load_lds((const __attribute__((address_space(1))) u32*)ga,
                                       (__attribute__((address_space(3))) u32*)la, 16, 0, 0);
      __builtin_amdgcn_global_load_lds((const __attribute__((address_space(1))) u32*)gb,
                                       (__attribute__((address_space(3))) u32*)lb, 16, 0, 0);
    }
    __syncthreads();
    for (int ks = 0; ks < 2; ++ks) {
      bfrag a[4], b[4];
      for (int mi = 0; mi < 4; ++mi) {
        int r = wm + mi * 16 + l15;
        int qs = (ks * 4 + l4) ^ (r & 7);
        a[mi] = *(const bfrag*)&lA[r * 64 + qs * 8];
      }
      for (int ni = 0; ni < 4; ++ni) {
        int r = wn + ni * 16 + l15;
        int qs = (ks * 4 + l4) ^ (r & 7);
        b[ni] = *(const bfrag*)&lB[r * 64 + qs * 8];
      }
      for (int mi = 0; mi < 4; ++mi)
        for (int ni = 0; ni < 4; ++ni)
          acc[mi][ni] = __builtin_amdgcn_mfma_f32_16x16x32_bf16(a[mi], b[ni], acc[mi][ni], 0, 0, 0);
    }
  }
  for (int ni = 0; ni < 4; ++ni) {
    int col = n0 + wn + ni * 16 + l15;
    if (col >= Nreal) continue;
    int bcol = permb ? (((col & 3) << 9) | (col >> 2)) : col;
    float bs = bias ? bias[bcol] : 0.0f;
    for (int mi = 0; mi < 4; ++mi) {
      int rb = m0 + wm + mi * 16 + l4 * 4;
      facc v = acc[mi][ni];
      C[(size_t)(rb + 0) * ldc + col] = v[0] + bs;
      C[(size_t)(rb + 1) * ldc + col] = v[1] + bs;
      C[(size_t)(rb + 2) * ldc + col] = v[2] + bs;
      C[(size_t)(rb + 3) * ldc + col] = v[3] + bs;
    }
  }
}

// h circles: u64 [129 slots][4096]; slot s consumed at step s; slot s+1 stored
// for all s. Flags: flag[rank] = 1 + latest slot stored (per producer block).

// ---------------- enc1: single-cell recurrence, XW input
__global__ __launch_bounds__(512, 1) void k_rec1(const float* __restrict__ XW,
                                                 const short* __restrict__ UT,
                                                 u64* __restrict__ hbuf,
                                                 u32* __restrict__ fown,
                                                 float* __restrict__ hfin,
                                                 float* __restrict__ cfin) {
  __shared__ short lh[2][16][520];
  __shared__ float zt[8][16][20];
  const int rank = blockIdx.x;
  const int tid = threadIdx.x;
  const int wv = tid >> 6, lane = tid & 63;
  const int l15 = lane & 15, l4 = lane >> 4;
  const int kh = wv >> 2;
  const int gw = rank * 4 + (wv & 3);
  const int bb = lane >> 2, jj = lane & 3;
  const int hidx = gw * 4 + jj;

  bfrag ur[8];
  {
    const short* ub = UT + (size_t)(gw * 16 + l15) * Hq + kh * 256 + l4 * 8;
    #pragma unroll
    for (int ks = 0; ks < 8; ++ks) ur[ks] = *(const bfrag*)&ub[ks * 32];
  }
  float c = 0.0f;
  if (wv < 4 && (jj & 1) == 0)
    ic_store64(&hbuf[(bb * Hq + hidx) >> 1], 0ull);    // h(-1)=0
  asm volatile("s_waitcnt vmcnt(0)" ::: "memory");
  __syncthreads();
  if (tid == 0) ic_store32(&fown[rank * FSTRIDE], 1u);

  for (int s = 0; s < Tq; ++s) {
    f32x4 xg = {};
    if (wv < 4) xg = *(const f32x4*)&XW[(size_t)(s * Bq + bb) * G4H + hidx * 4];
    const u64* ph = hbuf + (size_t)s * 4096 + tid;
    u64 v[8];
    for (int tries = 0;; ++tries) {          // fast path: 1-RT sentinel sweep
      #pragma unroll
      for (int it = 0; it < 8; ++it) v[it] = ic_load64(&ph[it * 512]);
      u32 bad = 0;
      #pragma unroll
      for (int it = 0; it < 8; ++it) bad |= (((u32)v[it] & 0xFFFFu) == SENTW);
      if (!__syncthreads_or((int)bad) || tries >= 8) break;
      waitf(fown, (u32)(s + 1));             // cheap wait: 128B flag poll
    }
    stage_h(&lh[0][0][0], &lh[1][0][0], v);
    __syncthreads();
    facc a0 = {}, a1 = {};
    #pragma unroll
    for (int ks = 0; ks < 8; ++ks) {
      int bo = kh * 512 + ks * 64 + l4 * 16;
      bfrag ah = *(const bfrag*)swz(&lh[0][0][0], l15, bo);
      bfrag al = *(const bfrag*)swz(&lh[1][0][0], l15, bo);
      a0 = __builtin_amdgcn_mfma_f32_16x16x32_bf16(ah, ur[ks], a0, 0, 0, 0);
      a1 = __builtin_amdgcn_mfma_f32_16x16x32_bf16(al, ur[ks], a1, 0, 0, 0);
    }
    a0 += a1;
    *(f32x4*)&zt[wv][l15][l4 * 4] = a0;
    __syncthreads();
    if (wv < 4) {
      float zi = zt[wv][4 * jj + 0][bb] + zt[wv + 4][4 * jj + 0][bb] + xg[0];
      float zf = zt[wv][4 * jj + 1][bb] + zt[wv + 4][4 * jj + 1][bb] + xg[1];
      float zg = zt[wv][4 * jj + 2][bb] + zt[wv + 4][4 * jj + 2][bb] + xg[2];
      float zo = zt[wv][4 * jj + 3][bb] + zt[wv + 4][4 * jj + 3][bb] + xg[3];
      c = sigm(zf) * c + sigm(zi) * tanhf(zg);
      float hN = sigm(zo) * tanhf(c);
      int hi_ = (int)(unsigned short)f2bf(hN);
      int lo_ = (int)(unsigned short)f2bf(hN - bf2f((short)hi_));
      int hi2 = __shfl_xor(hi_, 1), lo2 = __shfl_xor(lo_, 1);
      if ((jj & 1) == 0) {
        u64 pv = (u64)((u32)hi_ | ((u32)hi2 << 16)) | ((u64)((u32)lo_ | ((u32)lo2 << 16)) << 32);
        ic_store64(&hbuf[(size_t)(s + 1) * 4096 + ((bb * Hq + hidx) >> 1)], pv);
      }
      if (s == Tq - 1) { hfin[bb * Hq + hidx] = hN; cfin[bb * Hq + hidx] = c; }
    }
    asm volatile("s_waitcnt vmcnt(0)" ::: "memory");   // data acked at IC
    __syncthreads();                                    // all waves drained
    if (tid == 0) ic_store32(&fown[rank * FSTRIDE], (u32)(s + 2));
  }
}

// ---------------- generic cell(s): carry ready at launch.
struct CellP {
  const short* ur;      // recurrent weights' (gate-interleaved, [2048][512])
  const short* wr;      // input weights'
  const float* bias;
  const float* hcar;    // carry h (f32, ready)
  const float* ccar;    // carry c
  u64*  own;            // own h circle [129][4096]
  const u64* inp;       // input h circle (consume slot s+1)
  u32*  fOwn;           // own circle flags
  const u32* fInp;      // input circle flags (nullptr = materialized, plain loads)
  short* seq;           // optional: hi out [T*B, H]
  short* dec;           // optional: hi out at (b*Tq+s)*(2H)
  float* hfin;          // optional finals
  float* cfin;
};
struct Params2 { CellP c[2]; };

__global__ __launch_bounds__(512, 1) void k_cells(Params2 prm) {
  __shared__ short pl[4][16][520];
  __shared__ float zt[8][16][20];
  const int grp = blockIdx.x >> 5, rank = blockIdx.x & 31;
  const CellP P = grp ? prm.c[1] : prm.c[0];
  const int tid = threadIdx.x;
  const int wv = tid >> 6, lane = tid & 63;
  const int l15 = lane & 15, l4 = lane >> 4;
  const int kh = wv >> 2;
  const int gw = rank * 4 + (wv & 3);
  const int bb = lane >> 2, jj = lane & 3;
  const int hidx = gw * 4 + jj;
  const int idx = bb * Hq + hidx;

  bfrag ur[8], wr[8];
  {
    size_t ro = (size_t)(gw * 16 + l15) * Hq + kh * 256 + l4 * 8;
    #pragma unroll
    for (int ks = 0; ks < 8; ++ks) {
      ur[ks] = *(const bfrag*)&P.ur[ro + ks * 32];
      wr[ks] = *(const bfrag*)&P.wr[ro + ks * 32];
    }
  }
  float bi = 0, bf_ = 0, bg_ = 0, bo_ = 0, c = 0.0f;
  if (wv < 4) {
    bi = P.bias[hidx]; bf_ = P.bias[Hq + hidx];
    bg_ = P.bias[2 * Hq + hidx]; bo_ = P.bias[3 * Hq + hidx];
    float hv = P.hcar[idx];
    c = P.ccar[idx];
    int hi_ = (int)(unsigned short)f2bf(hv);
    int lo_ = (int)(unsigned short)f2bf(hv - bf2f((short)hi_));
    int hi2 = __shfl_xor(hi_, 1), lo2 = __shfl_xor(lo_, 1);
    if ((jj & 1) == 0) {
      u64 v = (u64)((u32)hi_ | ((u32)hi2 << 16)) | ((u64)((u32)lo_ | ((u32)lo2 << 16)) << 32);
      ic_store64(&P.own[idx >> 1], v);
    }
  }
  asm volatile("s_waitcnt vmcnt(0)" ::: "memory");
  __syncthreads();
  if (tid == 0) ic_store32(&P.fOwn[rank * FSTRIDE], 1u);

  for (int s = 0; s < Tq; ++s) {
    u64 v[8], vx[8];
    const u64* ph = P.own + (size_t)s * 4096 + tid;
    const u64* px = P.inp + (size_t)(s + 1) * 4096 + tid;
    if (P.fInp) {             // concurrent producer: dual sentinel sweep + flag wait
      for (int tries = 0;; ++tries) {
        #pragma unroll
        for (int it = 0; it < 8; ++it) v[it]  = ic_load64(&ph[it * 512]);
        #pragma unroll
        for (int it = 0; it < 8; ++it) vx[it] = ic_load64(&px[it * 512]);
        u32 bad = 0;
        #pragma unroll
        for (int it = 0; it < 8; ++it) {
          bad |= (((u32)v[it]  & 0xFFFFu) == SENTW);
          bad |= (((u32)vx[it] & 0xFFFFu) == SENTW);
        }
        if (!__syncthreads_or((int)bad) || tries >= 8) break;
        waitf2(P.fOwn, (u32)(s + 1), P.fInp, (u32)(s + 2));
      }
    } else {                  // input fully materialized: plain cached loads
      #pragma unroll
      for (int it = 0; it < 8; ++it) vx[it] = px[it * 512];
      for (int tries = 0;; ++tries) {
        #pragma unroll
        for (int it = 0; it < 8; ++it) v[it] = ic_load64(&ph[it * 512]);
        u32 bad = 0;
        #pragma unroll
        for (int it = 0; it < 8; ++it) bad |= (((u32)v[it] & 0xFFFFu) == SENTW);
        if (!__syncthreads_or((int)bad) || tries >= 8) break;
        waitf(P.fOwn, (u32)(s + 1));
      }
    }
    stage_h(&pl[0][0][0], &pl[1][0][0], v);
    stage_h(&pl[2][0][0], &pl[3][0][0], vx);
    __syncthreads();

    facc a0 = {}, a1 = {}, a2 = {}, a3 = {};
    #pragma unroll
    for (int ks = 0; ks < 8; ++ks) {
      int bo = kh * 512 + ks * 64 + l4 * 16;
      bfrag hh = *(const bfrag*)swz(&pl[0][0][0], l15, bo);
      bfrag hl = *(const bfrag*)swz(&pl[1][0][0], l15, bo);
      bfrag xh = *(const bfrag*)swz(&pl[2][0][0], l15, bo);
      bfrag xl = *(const bfrag*)swz(&pl[3][0][0], l15, bo);
      a0 = __builtin_amdgcn_mfma_f32_16x16x32_bf16(hh, ur[ks], a0, 0, 0, 0);
      a1 = __builtin_amdgcn_mfma_f32_16x16x32_bf16(hl, ur[ks], a1, 0, 0, 0);
      a2 = __builtin_amdgcn_mfma_f32_16x16x32_bf16(xh, wr[ks], a2, 0, 0, 0);
      a3 = __builtin_amdgcn_mfma_f32_16x16x32_bf16(xl, wr[ks], a3, 0, 0, 0);
    }
    a0 += a1; a0 += a2; a0 += a3;
    *(f32x4*)&zt[wv][l15][l4 * 4] = a0;
    __syncthreads();

    if (wv < 4) {
      float zi = zt[wv][4 * jj + 0][bb] + zt[wv + 4][4 * jj + 0][bb] + bi;
      float zf = zt[wv][4 * jj + 1][bb] + zt[wv + 4][4 * jj + 1][bb] + bf_;
      float zg = zt[wv][4 * jj + 2][bb] + zt[wv + 4][4 * jj + 2][bb] + bg_;
      float zo = zt[wv][4 * jj + 3][bb] + zt[wv + 4][4 * jj + 3][bb] + bo_;
      c = sigm(zf) * c + sigm(zi) * tanhf(zg);
      float hN = sigm(zo) * tanhf(c);
      int hi_ = (int)(unsigned short)f2bf(hN);
      int lo_ = (int)(unsigned short)f2bf(hN - bf2f((short)hi_));
      int hi2 = __shfl_xor(hi_, 1), lo2 = __shfl_xor(lo_, 1);
      if ((jj & 1) == 0) {
        u64 pv = (u64)((u32)hi_ | ((u32)hi2 << 16)) | ((u64)((u32)lo_ | ((u32)lo2 << 16)) << 32);
        ic_store64(&P.own[(size_t)(s + 1) * 4096 + (idx >> 1)], pv);
      }
      if (P.seq) P.seq[(size_t)(s * Bq + bb) * Hq + hidx] = (short)hi_;
      if (P.dec) P.dec[((size_t)bb * Tq + s) * (2 * Hq) + hidx] = (short)hi_;
      if (s == Tq - 1 && P.hfin) { P.hfin[idx] = hN; P.cfin[idx] = c; }
    }
    asm volatile("s_waitcnt vmcnt(0)" ::: "memory");
    __syncthreads();
    if (tid == 0) ic_store32(&P.fOwn[rank * FSTRIDE], (u32)(s + 2));
  }
}

// ---------------- batched attention over full seq2 (bf16 in/out; one block per (b,t))
__global__ __launch_bounds__(256) void k_attn(const short* __restrict__ seq2b,
                                              const short* __restrict__ hqb,
                                              short* __restrict__ decb) {
  int blk = blockIdx.x;
  int b = blk >> 7, t = blk & 127;
  __shared__ u32 q[256];
  __shared__ float part[256];
  __shared__ float p[Tq];
  int tid = threadIdx.x;
  q[tid] = *(const u32*)&hqb[(size_t)(t * Bq + b) * Hq + tid * 2];
  __syncthreads();
  {
    int s = tid >> 1, half = tid & 1;
    const u32* row = (const u32*)&seq2b[(size_t)(s * Bq + b) * Hq + half * 256];
    const u32* qh = q + half * 128;
    float a = 0.0f;
    #pragma unroll 8
    for (int k = 0; k < 128; ++k) {
      u32 r = row[k], qq = qh[k];
      a += asf(r << 16) * asf(qq << 16) + asf(r & 0xFFFF0000u) * asf(qq & 0xFFFF0000u);
    }
    part[tid] = a;
  }
  __syncthreads();
  if (tid < 64) {
    float v0 = part[2 * tid] + part[2 * tid + 1];
    float v1 = part[2 * (tid + 64)] + part[2 * (tid + 64) + 1];
    float mx = fmaxf(v0, v1);
    for (int off = 32; off; off >>= 1) mx = fmaxf(mx, __shfl_xor(mx, off));
    float e0 = __expf(v0 - mx), e1 = __expf(v1 - mx);
    float sm = e0 + e1;
    for (int off = 32; off; off >>= 1) sm += __shfl_xor(sm, off);
    float inv = 1.0f / sm;
    p[tid] = e0 * inv; p[tid + 64] = e1 * inv;
  }
  __syncthreads();
  float c0 = 0.0f, c1 = 0.0f;
  for (int s = 0; s < Tq; ++s) {
    float ps = p[s];
    u32 r = *(const u32*)&seq2b[(size_t)(s * Bq + b) * Hq + tid * 2];
    c0 += ps * asf(r << 16);
    c1 += ps * asf(r & 0xFFFF0000u);
  }
  u32 o = ((u32)(unsigned short)f2bf(c0)) | (((u32)(unsigned short)f2bf(c1)) << 16);
  *(u32*)&decb[(size_t)(b * Tq + t) * (2 * Hq) + Hq + tid * 2] = o;
}

// ---------------- row softmax over VO=32001 (in-place on d_out)
__global__ __launch_bounds__(256) void k_softmax(float* __restrict__ L) {
  int row = blockIdx.x;
  float* p = L + (size_t)row * VO;
  int tid = threadIdx.x;
  float m = -3.0e38f, s = 0.0f;
  for (int i = tid; i < VO; i += 256) {
    float v = p[i];
    float mn = fmaxf(m, v);
    s = s * __expf(m - mn) + __expf(v - mn);
    m = mn;
  }
  __shared__ float sm[256], ss[256];
  sm[tid] = m; ss[tid] = s;
  __syncthreads();
  for (int off = 128; off; off >>= 1) {
    if (tid < off) {
      float m2 = sm[tid + off], s2 = ss[tid + off];
      float mn = fmaxf(sm[tid], m2);
      ss[tid] = ss[tid] * __expf(sm[tid] - mn) + s2 * __expf(m2 - mn);
      sm[tid] = mn;
    }
    __syncthreads();
  }
  float M = sm[0], IS = 1.0f / ss[0];
  for (int i = tid; i < VO; i += 256) {
    p[i] = __expf(p[i] - M) * IS;
  }
}

// =============================================================================
extern "C" void kernel_launch(void* const* d_in, const int* in_sizes, int n_in,
                              void* d_out, int out_size, void* d_ws, size_t ws_size,
                              hipStream_t stream) {
  const int*   tokens = (const int*)d_in[0];
  const float* emb    = (const float*)d_in[1];
  const float* W1     = (const float*)d_in[2];
  const float* U1     = (const float*)d_in[3];
  const float* b1     = (const float*)d_in[4];
  const float* W2     = (const float*)d_in[5];
  const float* U2     = (const float*)d_in[6];
  const float* b2     = (const float*)d_in[7];
  const float* Wd1    = (const float*)d_in[8];
  const float* Ud1    = (const float*)d_in[9];
  const float* bd1    = (const float*)d_in[10];
  const float* Wd2    = (const float*)d_in[11];
  const float* Ud2    = (const float*)d_in[12];
  const float* bd2    = (const float*)d_in[13];
  const float* Wo     = (const float*)d_in[14];
  const float* bo     = (const float*)d_in[15];
  float* out = (float*)d_out;

  size_t off = 0;
  char* base = (char*)d_ws;
  auto alloc = [&](size_t bytes) -> void* {
    void* p = base + off;
    off += (bytes + 255) & ~(size_t)255;
    return p;
  };
  short* x_bf    = (short*)alloc((size_t)MR * Dq * 2);
  short* W1T     = (short*)alloc((size_t)G4H * Dq * 2);
  short* WoT     = (short*)alloc((size_t)NPAD * (2 * Hq) * 2);
  short* U1T     = (short*)alloc((size_t)G4H * Hq * 2);
  short* U2T     = (short*)alloc((size_t)G4H * Hq * 2);
  short* W2T     = (short*)alloc((size_t)G4H * Hq * 2);
  short* Ud1T    = (short*)alloc((size_t)G4H * Hq * 2);
  short* Wd1T    = (short*)alloc((size_t)G4H * Hq * 2);
  short* Ud2T    = (short*)alloc((size_t)G4H * Hq * 2);
  short* Wd2T    = (short*)alloc((size_t)G4H * Hq * 2);
  float* XW      = (float*)alloc((size_t)MR * G4H * 4);
  short* seq2_bf = (short*)alloc((size_t)MR * Hq * 2);
  short* hBseqbf = (short*)alloc((size_t)MR * Hq * 2);
  short* dec_bf  = (short*)alloc((size_t)MR * 2 * Hq * 2);
  u64*   hflow   = (u64*)alloc((size_t)516 * 4096 * 8);   // 4 circles x 129 slots
  u32*   flags   = (u32*)alloc(4 * 32 * FSTRIDE * 4);     // 4 circles x 32 ranks
  float* h1f     = (float*)alloc(BH * 4);
  float* c1f     = (float*)alloc(BH * 4);
  float* h2f     = (float*)alloc(BH * 4);
  float* c2f     = (float*)alloc(BH * 4);
  u64* h1buf = hflow;
  u64* h2buf = hflow + (size_t)129 * 4096;
  u64* hAbuf = hflow + (size_t)258 * 4096;
  u64* hBbuf = hflow + (size_t)387 * 4096;
  u32* f1 = flags;
  u32* f2 = flags + 32 * FSTRIDE;
  u32* fA = flags + 64 * FSTRIDE;
  u32* fB = flags + 96 * FSTRIDE;
  (void)ws_size; (void)in_sizes; (void)n_in; (void)out_size;

  // per-launch resets (kernel boundary flushes before first poll)
  {
    int n64 = 516 * 4096;
    k_fill<<<(n64 + 255) / 256, 256, 0, stream>>>(hflow, n64);
    k_fill0<<<(4 * 32 * FSTRIDE + 255) / 256, 256, 0, stream>>>(flags, 4 * 32 * FSTRIDE);
  }

  // weight transposes + bf16 conversion (gate-interleave on all recurrent mats)
  k_transcvt<<<dim3(G4H / 32, Dq / 32), 256, 0, stream>>>(W1, W1T, Dq, G4H, 1);
  k_transcvt<<<dim3(G4H / 32, Hq / 32), 256, 0, stream>>>(U1, U1T, Hq, G4H, 1);
  k_transcvt<<<dim3(G4H / 32, Hq / 32), 256, 0, stream>>>(U2, U2T, Hq, G4H, 1);
  k_transcvt<<<dim3(G4H / 32, Hq / 32), 256, 0, stream>>>(W2, W2T, Hq, G4H, 1);
  k_transcvt<<<dim3(G4H / 32, Hq / 32), 256, 0, stream>>>(Ud1, Ud1T, Hq, G4H, 1);
  k_transcvt<<<dim3(G4H / 32, Hq / 32), 256, 0, stream>>>(Wd1, Wd1T, Hq, G4H, 1);
  k_transcvt<<<dim3(G4H / 32, Hq / 32), 256, 0, stream>>>(Ud2, Ud2T, Hq, G4H, 1);
  k_transcvt<<<dim3(G4H / 32, Hq / 32), 256, 0, stream>>>(Wd2, Wd2T, Hq, G4H, 1);
  k_transcvt<<<dim3(NPAD / 32, (2 * Hq) / 32), 256, 0, stream>>>(Wo, WoT, 2 * Hq, VO, 0);

  k_gather<<<MR, 256, 0, stream>>>(tokens, emb, x_bf);

  // enc1: input projection GEMM + isolated single-cell recurrence
  k_gemm<<<dim3(G4H / 128, MR / 128), 256, 0, stream>>>(x_bf, W1T, XW, b1, MR, G4H, Dq, G4H, 1);
  k_rec1<<<32, 512, 0, stream>>>(XW, U1T, h1buf, f1, h1f, c1f);

  // enc2 (grp0) || decA (grp1): carries = enc1 finals (ready at launch).
  {
    Params2 p;
    p.c[0] = { U2T, W2T, b2,  h1f, c1f, h2buf, h1buf, f2, nullptr,
               seq2_bf, nullptr, h2f, c2f };
    p.c[1] = { Ud1T, Wd1T, bd1, h1f, c1f, hAbuf, h2buf, fA, f2,
               nullptr, nullptr, nullptr, nullptr };
    k_cells<<<64, 512, 0, stream>>>(p);
  }

  // decB: carry = enc2 finals; input = hAbuf (materialized, plain loads)
  {
    Params2 p;
    p.c[0] = { Ud2T, Wd2T, bd2, h2f, c2f, hBbuf, hAbuf, fB, nullptr,
               hBseqbf, dec_bf, nullptr, nullptr };
    p.c[1] = p.c[0];
    k_cells<<<32, 512, 0, stream>>>(p);
  }

  // attention + logits + softmax
  k_attn<<<MR, 256, 0, stream>>>(seq2_bf, hBseqbf, dec_bf);
  k_gemm<<<dim3(NPAD / 128, MR / 128), 256, 0, stream>>>(dec_bf, WoT, out, bo, MR, VO, 2 * Hq, VO, 0);
  k_softmax<<<MR, 256, 0, stream>>>(out);
}